// Round 5
// baseline (2588.328 us; speedup 1.0000x reference)
//
#include <hip/hip_runtime.h>
#include <cstdint>

// Shapes
#define BB 2
#define HH_ 256
#define WW_ 256
#define CC 96
#define NTOK 65536           // H*W
#define MTOK 131072          // B*N
#define HEADS 6
#define WS 16
#define WSQ 256
#define HEAD_D 16
#define TOPK 64
#define HID 12
#define MLP_ 192

typedef short v8s __attribute__((ext_vector_type(8)));
typedef float v4f __attribute__((ext_vector_type(4)));

__device__ __forceinline__ float gelu_f(float v) {
  return 0.5f * v * (1.0f + erff(v * 0.70710678118654752440f));
}
__device__ __forceinline__ float lrelu_f(float v) { return v >= 0.0f ? v : 0.2f * v; }
__device__ __forceinline__ unsigned short bf16r(float f) {
  unsigned u = __float_as_uint(f);
  unsigned r = u + 0x7fffu + ((u >> 16) & 1u);
  return (unsigned short)(r >> 16);
}

// ---------------- LayerNorm over C=96: one wave per token ----------------
__global__ __launch_bounds__(256) void ln_kernel(const float* __restrict__ in,
    const float* __restrict__ gam, const float* __restrict__ bet, float* __restrict__ out) {
  int wid = blockIdx.x * 4 + (threadIdx.x >> 6);
  int lane = threadIdx.x & 63;
  const float* row = in + (size_t)wid * CC;
  float v0 = row[lane];
  float v1 = (lane < 32) ? row[64 + lane] : 0.0f;
  float s = v0 + v1;
  #pragma unroll
  for (int off = 32; off; off >>= 1) s += __shfl_xor(s, off);
  float mean = s * (1.0f / 96.0f);
  float d0 = v0 - mean;
  float d1 = (lane < 32) ? (v1 - mean) : 0.0f;
  float q = d0 * d0 + d1 * d1;
  #pragma unroll
  for (int off = 32; off; off >>= 1) q += __shfl_xor(q, off);
  float r = rsqrtf(q * (1.0f / 96.0f) + 1e-5f);
  float* orow = out + (size_t)wid * CC;
  orow[lane] = d0 * r * gam[lane] + bet[lane];
  if (lane < 32) orow[64 + lane] = d1 * r * gam[64 + lane] + bet[64 + lane];
}

// ---------------- Global average pool ----------------
__global__ __launch_bounds__(128) void pool_kernel(const float* __restrict__ A, float* __restrict__ pooled) {
  int c = threadIdx.x;
  if (c >= CC) return;
  int b = blockIdx.y;
  int t0 = blockIdx.x * 512;
  const float* base = A + ((size_t)b * NTOK + t0) * CC + c;
  float acc = 0.0f;
  #pragma unroll 8
  for (int t = 0; t < 512; t++) acc += base[(size_t)t * CC];
  atomicAdd(&pooled[b * CC + c], acc);
}

// ---------------- Gate MLP ----------------
__global__ __launch_bounds__(64) void gate_kernel(const float* __restrict__ pooled,
    const float* __restrict__ w1, const float* __restrict__ b1,
    const float* __restrict__ w2, const float* __restrict__ b2, float* __restrict__ gv) {
  __shared__ float hb[BB][HID];
  __shared__ float lb[BB][3];
  int tid = threadIdx.x;
  if (tid < BB * HID) {
    int b = tid / HID, o = tid % HID;
    float s = b1[o];
    for (int c = 0; c < CC; c++) s += (pooled[b * CC + c] * (1.0f / 65536.0f)) * w1[o * CC + c];
    hb[b][o] = fmaxf(s, 0.0f);
  }
  __syncthreads();
  if (tid < BB * 3) {
    int b = tid / 3, j = tid % 3;
    float s = b2[j];
    for (int o = 0; o < HID; o++) s += hb[b][o] * w2[j * HID + o];
    lb[b][j] = s;
  }
  __syncthreads();
  if (tid < BB) {
    float m = fmaxf(lb[tid][0], fmaxf(lb[tid][1], lb[tid][2]));
    float e0 = __expf(lb[tid][0] - m), e1 = __expf(lb[tid][1] - m), e2 = __expf(lb[tid][2] - m);
    float inv = 1.0f / (e0 + e1 + e2);
    gv[tid * 3 + 0] = e0 * inv; gv[tid * 3 + 1] = e1 * inv; gv[tid * 3 + 2] = e2 * inv;
  }
}

// ---------------- MFMA GEMM: 128x64 tile, bf16 16x16x32 ----------------
template <int K, int NO, int ACT, bool RESID, bool HASB>
__global__ __launch_bounds__(256, 4) void mgemm_kernel(const float* __restrict__ A,
    const float* __restrict__ W, const float* __restrict__ bias,
    const float* __restrict__ resid, float* __restrict__ out, int ostride, int rstride) {
  __shared__ __align__(16) unsigned short al[128][104];
  __shared__ __align__(16) unsigned short wl[64][104];
  int tid = threadIdx.x;
  int lane = tid & 63, wv = tid >> 6, quad = lane >> 4, to = lane & 15;
  int o0 = blockIdx.x * 64, p0 = blockIdx.y * 128;
  v4f acc[2][4];
  #pragma unroll
  for (int ni = 0; ni < 4; ni++) {
    float bv = 0.0f;
    if (HASB) { int o = o0 + ni * 16 + to; if (o < NO) bv = bias[o]; }
    #pragma unroll
    for (int mi = 0; mi < 2; mi++) acc[mi][ni] = (v4f){bv, bv, bv, bv};
  }
  for (int kc = 0; kc < K; kc += 96) {
    __syncthreads();
    {
      int r = tid & 127, half = tid >> 7;
      const float* ap = A + (size_t)(p0 + r) * K + kc + half * 48;
      #pragma unroll
      for (int g = 0; g < 3; g++) {
        float4 f0 = *(const float4*)(ap + g * 16);
        float4 f1 = *(const float4*)(ap + g * 16 + 4);
        float4 f2 = *(const float4*)(ap + g * 16 + 8);
        float4 f3 = *(const float4*)(ap + g * 16 + 12);
        uint4 u, v;
        u.x = (unsigned)bf16r(f0.x) | ((unsigned)bf16r(f0.y) << 16);
        u.y = (unsigned)bf16r(f0.z) | ((unsigned)bf16r(f0.w) << 16);
        u.z = (unsigned)bf16r(f1.x) | ((unsigned)bf16r(f1.y) << 16);
        u.w = (unsigned)bf16r(f1.z) | ((unsigned)bf16r(f1.w) << 16);
        v.x = (unsigned)bf16r(f2.x) | ((unsigned)bf16r(f2.y) << 16);
        v.y = (unsigned)bf16r(f2.z) | ((unsigned)bf16r(f2.w) << 16);
        v.z = (unsigned)bf16r(f3.x) | ((unsigned)bf16r(f3.y) << 16);
        v.w = (unsigned)bf16r(f3.z) | ((unsigned)bf16r(f3.w) << 16);
        *(uint4*)&al[r][half * 48 + g * 16] = u;
        *(uint4*)&al[r][half * 48 + g * 16 + 8] = v;
      }
    }
    {
      int r = tid & 63, q = tid >> 6;
      int o = o0 + r;
      if (o < NO) {
        const float* wp = W + (size_t)o * K + kc + q * 24;
        #pragma unroll
        for (int g = 0; g < 3; g++) {
          float4 f0 = *(const float4*)(wp + g * 8);
          float4 f1 = *(const float4*)(wp + g * 8 + 4);
          uint4 u;
          u.x = (unsigned)bf16r(f0.x) | ((unsigned)bf16r(f0.y) << 16);
          u.y = (unsigned)bf16r(f0.z) | ((unsigned)bf16r(f0.w) << 16);
          u.z = (unsigned)bf16r(f1.x) | ((unsigned)bf16r(f1.y) << 16);
          u.w = (unsigned)bf16r(f1.z) | ((unsigned)bf16r(f1.w) << 16);
          *(uint4*)&wl[r][q * 24 + g * 8] = u;
        }
      } else {
        uint4 z = make_uint4(0, 0, 0, 0);
        #pragma unroll
        for (int g = 0; g < 3; g++) *(uint4*)&wl[r][q * 24 + g * 8] = z;
      }
    }
    __syncthreads();
    #pragma unroll
    for (int ks = 0; ks < 3; ks++) {
      v8s af[2], bfr[4];
      #pragma unroll
      for (int mi = 0; mi < 2; mi++)
        af[mi] = *(const v8s*)&al[wv * 32 + mi * 16 + to][ks * 32 + quad * 8];
      #pragma unroll
      for (int ni = 0; ni < 4; ni++)
        bfr[ni] = *(const v8s*)&wl[ni * 16 + to][ks * 32 + quad * 8];
      #pragma unroll
      for (int mi = 0; mi < 2; mi++)
        #pragma unroll
        for (int ni = 0; ni < 4; ni++)
          acc[mi][ni] = __builtin_amdgcn_mfma_f32_16x16x32_bf16(af[mi], bfr[ni], acc[mi][ni], 0, 0, 0);
    }
  }
  #pragma unroll
  for (int mi = 0; mi < 2; mi++)
    #pragma unroll
    for (int ni = 0; ni < 4; ni++) {
      int o = o0 + ni * 16 + to;
      if (o < NO) {
        #pragma unroll
        for (int rg = 0; rg < 4; rg++) {
          int p = p0 + wv * 32 + mi * 16 + quad * 4 + rg;
          float v = acc[mi][ni][rg];
          if (ACT == 1) v = lrelu_f(v);
          else if (ACT == 2) v = gelu_f(v);
          if (RESID) v += resid[(size_t)p * rstride + o];
          out[(size_t)p * ostride + o] = v;
        }
      }
    }
}

// ---------------- Fused 3-expert w1 GEMM: one A read, 3x12 outputs + lrelu ----------------
__global__ __launch_bounds__(256, 4) void mgemm3_kernel(const float* __restrict__ A,
    const float* __restrict__ W0, const float* __restrict__ W1, const float* __restrict__ W2,
    const float* __restrict__ B0, const float* __restrict__ B1, const float* __restrict__ B2,
    float* __restrict__ o0p, float* __restrict__ o1p, float* __restrict__ o2p) {
  __shared__ __align__(16) unsigned short al[128][104];
  __shared__ __align__(16) unsigned short wl[48][104];
  int tid = threadIdx.x;
  int lane = tid & 63, wv = tid >> 6, quad = lane >> 4, to = lane & 15;
  int p0 = blockIdx.x * 128;
  const float* Wp[3] = {W0, W1, W2};
  const float* Bp[3] = {B0, B1, B2};
  float* Op[3] = {o0p, o1p, o2p};
  v4f acc[2][3];
  #pragma unroll
  for (int ni = 0; ni < 3; ni++) {
    float bv = (to < 12) ? Bp[ni][to] : 0.0f;
    #pragma unroll
    for (int mi = 0; mi < 2; mi++) acc[mi][ni] = (v4f){bv, bv, bv, bv};
  }
  {
    int r = tid & 127, half = tid >> 7;
    const float* ap = A + (size_t)(p0 + r) * 96 + half * 48;
    #pragma unroll
    for (int g = 0; g < 3; g++) {
      float4 f0 = *(const float4*)(ap + g * 16);
      float4 f1 = *(const float4*)(ap + g * 16 + 4);
      float4 f2 = *(const float4*)(ap + g * 16 + 8);
      float4 f3 = *(const float4*)(ap + g * 16 + 12);
      uint4 u, v;
      u.x = (unsigned)bf16r(f0.x) | ((unsigned)bf16r(f0.y) << 16);
      u.y = (unsigned)bf16r(f0.z) | ((unsigned)bf16r(f0.w) << 16);
      u.z = (unsigned)bf16r(f1.x) | ((unsigned)bf16r(f1.y) << 16);
      u.w = (unsigned)bf16r(f1.z) | ((unsigned)bf16r(f1.w) << 16);
      v.x = (unsigned)bf16r(f2.x) | ((unsigned)bf16r(f2.y) << 16);
      v.y = (unsigned)bf16r(f2.z) | ((unsigned)bf16r(f2.w) << 16);
      v.z = (unsigned)bf16r(f3.x) | ((unsigned)bf16r(f3.y) << 16);
      v.w = (unsigned)bf16r(f3.z) | ((unsigned)bf16r(f3.w) << 16);
      *(uint4*)&al[r][half * 48 + g * 16] = u;
      *(uint4*)&al[r][half * 48 + g * 16 + 8] = v;
    }
  }
  {
    int r = tid & 63, q = tid >> 6;
    if (r < 48) {
      int e = r >> 4, rr = r & 15;
      if (rr < 12) {
        const float* wp = Wp[e] + (size_t)rr * 96 + q * 24;
        #pragma unroll
        for (int g = 0; g < 3; g++) {
          float4 f0 = *(const float4*)(wp + g * 8);
          float4 f1 = *(const float4*)(wp + g * 8 + 4);
          uint4 u;
          u.x = (unsigned)bf16r(f0.x) | ((unsigned)bf16r(f0.y) << 16);
          u.y = (unsigned)bf16r(f0.z) | ((unsigned)bf16r(f0.w) << 16);
          u.z = (unsigned)bf16r(f1.x) | ((unsigned)bf16r(f1.y) << 16);
          u.w = (unsigned)bf16r(f1.z) | ((unsigned)bf16r(f1.w) << 16);
          *(uint4*)&wl[r][q * 24 + g * 8] = u;
        }
      } else {
        uint4 z = make_uint4(0, 0, 0, 0);
        #pragma unroll
        for (int g = 0; g < 3; g++) *(uint4*)&wl[r][q * 24 + g * 8] = z;
      }
    }
  }
  __syncthreads();
  #pragma unroll
  for (int ks = 0; ks < 3; ks++) {
    v8s af[2], bfr[3];
    #pragma unroll
    for (int mi = 0; mi < 2; mi++)
      af[mi] = *(const v8s*)&al[wv * 32 + mi * 16 + to][ks * 32 + quad * 8];
    #pragma unroll
    for (int ni = 0; ni < 3; ni++)
      bfr[ni] = *(const v8s*)&wl[ni * 16 + to][ks * 32 + quad * 8];
    #pragma unroll
    for (int mi = 0; mi < 2; mi++)
      #pragma unroll
      for (int ni = 0; ni < 3; ni++)
        acc[mi][ni] = __builtin_amdgcn_mfma_f32_16x16x32_bf16(af[mi], bfr[ni], acc[mi][ni], 0, 0, 0);
  }
  if (to < 12) {
    #pragma unroll
    for (int mi = 0; mi < 2; mi++)
      #pragma unroll
      for (int ni = 0; ni < 3; ni++) {
        #pragma unroll
        for (int rg = 0; rg < 4; rg++) {
          int p = p0 + wv * 32 + mi * 16 + quad * 4 + rg;
          Op[ni][(size_t)p * 12 + to] = lrelu_f(acc[mi][ni][rg]);
        }
      }
  }
}

// ---------------- Vector GEMM (12x12 pw) ----------------
template <int K, int KC, int NO, int ACT, bool RESID, bool HASB>
__global__ __launch_bounds__(256) void gemm_kernel(const float* __restrict__ in,
    const float* __restrict__ w, const float* __restrict__ bias,
    const float* __restrict__ resid, float* __restrict__ out, int ostride, int rstride) {
  __shared__ __align__(16) float xs[64][KC + 4];
  __shared__ __align__(16) float ws[64][KC + 4];
  int tid = threadIdx.x;
  int p0 = blockIdx.x * 64;
  int o0 = blockIdx.y * 64;
  int to = tid & 15, tp = tid >> 4;
  float acc[4][4];
  #pragma unroll
  for (int j = 0; j < 4; j++) {
    float bv = 0.0f;
    if (HASB) { int o = o0 + to + 16 * j; if (o < NO) bv = bias[o]; }
    #pragma unroll
    for (int i = 0; i < 4; i++) acc[i][j] = bv;
  }
  for (int kc = 0; kc < K; kc += KC) {
    __syncthreads();
    for (int idx = tid; idx < 64 * (KC / 4); idx += 256) {
      int p = idx / (KC / 4), c4 = idx % (KC / 4);
      *(float4*)&xs[p][c4 * 4] = *(const float4*)&in[(size_t)(p0 + p) * K + kc + c4 * 4];
    }
    for (int idx = tid; idx < 64 * (KC / 4); idx += 256) {
      int r = idx / (KC / 4), c4 = idx % (KC / 4);
      int o = o0 + r;
      float4 v = make_float4(0.f, 0.f, 0.f, 0.f);
      if (o < NO) v = *(const float4*)&w[(size_t)o * K + kc + c4 * 4];
      *(float4*)&ws[r][c4 * 4] = v;
    }
    __syncthreads();
    #pragma unroll 4
    for (int cc = 0; cc < KC; cc += 4) {
      float4 xv[4], wv[4];
      #pragma unroll
      for (int i = 0; i < 4; i++) xv[i] = *(const float4*)&xs[tp + 16 * i][cc];
      #pragma unroll
      for (int j = 0; j < 4; j++) wv[j] = *(const float4*)&ws[to + 16 * j][cc];
      #pragma unroll
      for (int i = 0; i < 4; i++)
        #pragma unroll
        for (int j = 0; j < 4; j++)
          acc[i][j] += xv[i].x * wv[j].x + xv[i].y * wv[j].y + xv[i].z * wv[j].z + xv[i].w * wv[j].w;
    }
  }
  #pragma unroll
  for (int i = 0; i < 4; i++) {
    int p = p0 + tp + 16 * i;
    #pragma unroll
    for (int j = 0; j < 4; j++) {
      int o = o0 + to + 16 * j;
      if (o < NO) {
        float v = acc[i][j];
        if (ACT == 1) v = lrelu_f(v);
        else if (ACT == 2) v = gelu_f(v);
        if (RESID) v += resid[(size_t)p * rstride + o];
        out[(size_t)p * ostride + o] = v;
      }
    }
  }
}

// ---------------- Depthwise KxK conv, float4 channel groups ----------------
template <int KSZ, int CG, int ACT, bool RESID>
__global__ __launch_bounds__(256) void dwconv4_kernel(const float* __restrict__ in,
    const float* __restrict__ wt, const float* __restrict__ wb,
    const float* __restrict__ resid, float* __restrict__ out,
    int istride, int ostride, int rstride) {
  int e = blockIdx.x * 256 + threadIdx.x;
  int cg = e % CG;
  int pix = e / CG;
  int c = cg * 4;
  int b = pix >> 16, n = pix & 65535, h = n >> 8, w = n & 255;
  const int P = (KSZ - 1) / 2;
  float4 acc = *(const float4*)&wb[c];
  #pragma unroll
  for (int ky = 0; ky < KSZ; ky++) {
    int hh = h + ky - P;
    if (hh < 0 || hh >= HH_) continue;
    #pragma unroll
    for (int kx = 0; kx < KSZ; kx++) {
      int ww = w + kx - P;
      if (ww < 0 || ww >= WW_) continue;
      float4 iv = *(const float4*)&in[((size_t)(b << 16) + (hh << 8) + ww) * istride + c];
      int wi0 = ky * KSZ + kx;
      acc.x += wt[(c + 0) * KSZ * KSZ + wi0] * iv.x;
      acc.y += wt[(c + 1) * KSZ * KSZ + wi0] * iv.y;
      acc.z += wt[(c + 2) * KSZ * KSZ + wi0] * iv.z;
      acc.w += wt[(c + 3) * KSZ * KSZ + wi0] * iv.w;
    }
  }
  if (ACT == 1) {
    acc.x = lrelu_f(acc.x); acc.y = lrelu_f(acc.y); acc.z = lrelu_f(acc.z); acc.w = lrelu_f(acc.w);
  } else if (ACT == 2) {
    acc.x = gelu_f(acc.x); acc.y = gelu_f(acc.y); acc.z = gelu_f(acc.z); acc.w = gelu_f(acc.w);
  }
  if (RESID) {
    float4 rv = *(const float4*)&resid[(size_t)pix * rstride + c];
    acc.x += rv.x; acc.y += rv.y; acc.z += rv.z; acc.w += rv.w;
  }
  *(float4*)&out[(size_t)pix * ostride + c] = acc;
}

// ---------------- MoE combine ----------------
__global__ __launch_bounds__(256) void moe_combine_kernel(float* __restrict__ A,
    const float* __restrict__ t3a, const float* __restrict__ t3b, const float* __restrict__ t3c,
    const float* __restrict__ w2a, const float* __restrict__ w2b, const float* __restrict__ w2c,
    const float* __restrict__ b2a, const float* __restrict__ b2b, const float* __restrict__ b2c,
    const float* __restrict__ gv, const float* __restrict__ ms) {
  int e = blockIdx.x * 256 + threadIdx.x;
  int c = e % CC, pix = e / CC, b = pix >> 16;
  float sa = b2a[c], sb = b2b[c], sc = b2c[c];
  #pragma unroll
  for (int h2 = 0; h2 < HID; h2++) {
    sa += t3a[(size_t)pix * HID + h2] * w2a[c * HID + h2];
    sb += t3b[(size_t)pix * HID + h2] * w2b[c * HID + h2];
    sc += t3c[(size_t)pix * HID + h2] * w2c[c * HID + h2];
  }
  float o = gv[b * 3 + 0] * sa + gv[b * 3 + 1] * sb + gv[b * 3 + 2] * sc;
  A[e] += ms[0] * o;
}

// ---------------- Bias table ----------------
__global__ __launch_bounds__(256) void bias_kernel(const int* __restrict__ rpi,
    const float* __restrict__ rpb, float* __restrict__ biasT) {
  int idx = blockIdx.x * 256 + threadIdx.x;
  int h = idx >> 16, nm = idx & 65535;
  biasT[idx] = rpb[rpi[nm] * HEADS + h];
}

// ---------------- Wave-owned windowed attention: 1 barrier/block ----------------
// Block = (window, head), 4 waves; wave wv owns rows [64wv, 64wv+64) in 4 chunks of 16.
// S^T = K·Q^T via MFMA (A=K, B=Q) -> lane holds row 'to', 4 consecutive cols -> b64 LDS ops.
// Exact top-64 on 16-bit keys (radix-ballot), AV via MFMA. O preloaded with lepe; O += P@V.
__global__ __launch_bounds__(256, 3) void attn_kernel(const float* __restrict__ X,
    const float* __restrict__ biasT, float* __restrict__ O) {
  __shared__ __align__(16) unsigned short kb[256][20];    // K bf16, stride 10 dw
  __shared__ __align__(16) unsigned short vt[16][268];    // V^T bf16, stride 134 dw
  __shared__ __align__(16) unsigned short spw[4][16][276];// per-wave S-keys/P, stride 138 dw
  int tid = threadIdx.x;
  int wi = blockIdx.x, hh = blockIdx.y;
  int b = wi >> 8, wrem = wi & 255, wy = wrem >> 4, wx = wrem & 15;
  int lane = tid & 63, wv_ = tid >> 6, quad = lane >> 4, to = lane & 15;

  // ---- stage K and V^T (one token per thread) ----
  {
    int m = tid;
    int nm = (((wy << 4) + (m >> 4)) << 8) | ((wx << 4) + (m & 15));
    size_t xb = ((size_t)(b << 16) + nm) * 288 + hh * 16;
    float kr[16], vr[16];
    *(float4*)&kr[0]  = *(const float4*)(X + xb + 96);
    *(float4*)&kr[4]  = *(const float4*)(X + xb + 100);
    *(float4*)&kr[8]  = *(const float4*)(X + xb + 104);
    *(float4*)&kr[12] = *(const float4*)(X + xb + 108);
    *(float4*)&vr[0]  = *(const float4*)(X + xb + 192);
    *(float4*)&vr[4]  = *(const float4*)(X + xb + 196);
    *(float4*)&vr[8]  = *(const float4*)(X + xb + 200);
    *(float4*)&vr[12] = *(const float4*)(X + xb + 204);
    #pragma unroll
    for (int g = 0; g < 4; g++) {
      uint2 u;
      u.x = (unsigned)bf16r(kr[4 * g])     | ((unsigned)bf16r(kr[4 * g + 1]) << 16);
      u.y = (unsigned)bf16r(kr[4 * g + 2]) | ((unsigned)bf16r(kr[4 * g + 3]) << 16);
      *(uint2*)&kb[m][4 * g] = u;
    }
    #pragma unroll
    for (int d = 0; d < 16; d++) vt[d][m] = bf16r(vr[d]);
  }
  __syncthreads();   // the only barrier

  for (int ci = 0; ci < 4; ci++) {
    int r0 = wv_ * 64 + ci * 16;
    // ---- Q fragment (B-operand): lane to -> row r0+to, k = quad*8+j (quad<2) ----
    v8s qf = (v8s){0, 0, 0, 0, 0, 0, 0, 0};
    if (quad < 2) {
      int tq = r0 + to;
      int nq = (((wy << 4) + (tq >> 4)) << 8) | ((wx << 4) + (tq & 15));
      const float* qp = X + ((size_t)(b << 16) + nq) * 288 + hh * 16 + quad * 8;
      float4 f0 = *(const float4*)qp;
      float4 f1 = *(const float4*)(qp + 4);
      union { uint2 u2[2]; v8s v; } tq2;
      tq2.u2[0].x = (unsigned)bf16r(f0.x * 0.25f) | ((unsigned)bf16r(f0.y * 0.25f) << 16);
      tq2.u2[0].y = (unsigned)bf16r(f0.z * 0.25f) | ((unsigned)bf16r(f0.w * 0.25f) << 16);
      tq2.u2[1].x = (unsigned)bf16r(f1.x * 0.25f) | ((unsigned)bf16r(f1.y * 0.25f) << 16);
      tq2.u2[1].y = (unsigned)bf16r(f1.z * 0.25f) | ((unsigned)bf16r(f1.w * 0.25f) << 16);
      qf = tq2.v;
    }
    // ---- S^T tiles: lane gets S[to][t*16+quad*4+reg]; store 16-bit keys (b64) ----
    #pragma unroll 4
    for (int t = 0; t < 16; t++) {
      v8s kf = (v8s){0, 0, 0, 0, 0, 0, 0, 0};
      if (quad < 2) {
        union { uint2 u2[2]; v8s v; } tk;
        tk.u2[0] = *(const uint2*)&kb[t * 16 + to][quad * 8];
        tk.u2[1] = *(const uint2*)&kb[t * 16 + to][quad * 8 + 4];
        kf = tk.v;
      }
      const float* bp = biasT + ((size_t)hh << 16) + (size_t)(r0 + to) * 256 + t * 16 + quad * 4;
      float4 bv = *(const float4*)bp;
      v4f cf = {bv.x, bv.y, bv.z, bv.w};
      cf = __builtin_amdgcn_mfma_f32_16x16x32_bf16(kf, qf, cf, 0, 0, 0);
      uint2 kk;
      kk.x = (__float_as_uint(cf[1]) & 0xFFFF0000u) | (__float_as_uint(cf[0]) >> 16);
      kk.y = (__float_as_uint(cf[3]) & 0xFFFF0000u) | (__float_as_uint(cf[2]) >> 16);
      *(uint2*)&spw[wv_][to][t * 16 + quad * 4] = kk;
    }
    // ---- per-row softmax + exact top-64 (cols 4*lane..4*lane+3 per lane) ----
    #pragma unroll 1
    for (int r = 0; r < 16; r++) {
      uint2 kk = *(const uint2*)&spw[wv_][r][lane * 4];
      unsigned k0 = kk.x & 0xFFFFu, k1 = kk.x >> 16;
      unsigned k2 = kk.y & 0xFFFFu, k3 = kk.y >> 16;
      unsigned u0 = (k0 & 0x8000u) ? (k0 ^ 0xFFFFu) : (k0 | 0x8000u);
      unsigned u1 = (k1 & 0x8000u) ? (k1 ^ 0xFFFFu) : (k1 | 0x8000u);
      unsigned u2 = (k2 & 0x8000u) ? (k2 ^ 0xFFFFu) : (k2 | 0x8000u);
      unsigned u3 = (k3 & 0x8000u) ? (k3 ^ 0xFFFFu) : (k3 | 0x8000u);
      unsigned ad = u0 & u1 & u2 & u3;
      unsigned orr = u0 | u1 | u2 | u3;
      unsigned um = u0 > u1 ? u0 : u1;
      unsigned umb = u2 > u3 ? u2 : u3;
      um = um > umb ? um : umb;
      #pragma unroll
      for (int off = 32; off; off >>= 1) {
        ad &= __shfl_xor(ad, off);
        orr |= __shfl_xor(orr, off);
        unsigned t2 = __shfl_xor(um, off);
        um = um > t2 ? um : t2;
      }
      unsigned hm = (um & 0x8000u) ? (um - 0x8000u) : (um ^ 0xFFFFu);
      float xm = __uint_as_float(hm << 16);
      float e0 = __expf(__uint_as_float(k0 << 16) - xm);
      float e1 = __expf(__uint_as_float(k1 << 16) - xm);
      float e2 = __expf(__uint_as_float(k2 << 16) - xm);
      float e3 = __expf(__uint_as_float(k3 << 16) - xm);
      float sm = (e0 + e1) + (e2 + e3);
      #pragma unroll
      for (int off = 32; off; off >>= 1) sm += __shfl_xor(sm, off);
      float inv = 1.0f / sm;
      unsigned diff = ad ^ orr;
      unsigned cand = ad;
      if (diff) {
        int hb = 31 - __builtin_clz(diff);
        cand = ad & ~((1u << (hb + 1)) - 1u);
        for (int bit = hb; bit >= 0; --bit) {
          unsigned t_ = cand | (1u << bit);
          int cnt = __popcll(__ballot(u0 >= t_)) + __popcll(__ballot(u1 >= t_)) +
                    __popcll(__ballot(u2 >= t_)) + __popcll(__ballot(u3 >= t_));
          if (cnt >= TOPK) { cand = t_; if (cnt == TOPK) break; }
        }
      }
      int gcnt = __popcll(__ballot(u0 > cand)) + __popcll(__ballot(u1 > cand)) +
                 __popcll(__ballot(u2 > cand)) + __popcll(__ballot(u3 > cand));
      int need = TOPK - gcnt;
      unsigned long long q0 = __ballot(u0 == cand), q1 = __ballot(u1 == cand);
      unsigned long long q2 = __ballot(u2 == cand), q3 = __ballot(u3 == cand);
      unsigned long long lt = ((unsigned long long)1 << lane) - 1ull;
      int base = __popcll(q0 & lt) + __popcll(q1 & lt) + __popcll(q2 & lt) + __popcll(q3 & lt);
      int b0 = (int)((q0 >> lane) & 1ull), b1 = (int)((q1 >> lane) & 1ull), b2 = (int)((q2 >> lane) & 1ull);
      int pf0 = base, pf1 = base + b0, pf2 = pf1 + b1, pf3 = pf2 + b2;
      unsigned P0 = (u0 > cand || (u0 == cand && pf0 < need)) ? (unsigned)bf16r(e0 * inv) : 0u;
      unsigned P1 = (u1 > cand || (u1 == cand && pf1 < need)) ? (unsigned)bf16r(e1 * inv) : 0u;
      unsigned P2 = (u2 > cand || (u2 == cand && pf2 < need)) ? (unsigned)bf16r(e2 * inv) : 0u;
      unsigned P3 = (u3 > cand || (u3 == cand && pf3 < need)) ? (unsigned)bf16r(e3 * inv) : 0u;
      uint2 pw;
      pw.x = P0 | (P1 << 16);
      pw.y = P2 | (P3 << 16);
      *(uint2*)&spw[wv_][r][lane * 4] = pw;
    }
    // ---- AV via MFMA: A = P (m=row=to), B = V^T (n=dim=to), 8 K-chunks of 32 ----
    v4f oacc = {0.f, 0.f, 0.f, 0.f};
    #pragma unroll
    for (int kc = 0; kc < 8; kc++) {
      union { uint2 u2[2]; v8s v; } tp, tv;
      tp.u2[0] = *(const uint2*)&spw[wv_][to][kc * 32 + quad * 8];
      tp.u2[1] = *(const uint2*)&spw[wv_][to][kc * 32 + quad * 8 + 4];
      tv.u2[0] = *(const uint2*)&vt[to][kc * 32 + quad * 8];
      tv.u2[1] = *(const uint2*)&vt[to][kc * 32 + quad * 8 + 4];
      oacc = __builtin_amdgcn_mfma_f32_16x16x32_bf16(tp.v, tv.v, oacc, 0, 0, 0);
    }
    // ---- epilogue: D rows = r0+quad*4+reg, col d = to; O holds lepe ----
    #pragma unroll
    for (int rg = 0; rg < 4; rg++) {
      int tr = r0 + quad * 4 + rg;
      int no = (((wy << 4) + (tr >> 4)) << 8) | ((wx << 4) + (tr & 15));
      size_t oi = ((size_t)(b << 16) + no) * CC + hh * 16 + to;
      O[oi] += oacc[rg];
    }
  }
}

extern "C" void kernel_launch(void* const* d_in, const int* in_sizes, int n_in,
                              void* d_out, int out_size, void* d_ws, size_t ws_size,
                              hipStream_t stream) {
  (void)in_sizes; (void)n_in; (void)out_size; (void)ws_size;
  const float* x     = (const float*)d_in[0];
  const float* n1_g  = (const float*)d_in[1];
  const float* n1_b  = (const float*)d_in[2];
  const float* n2_g  = (const float*)d_in[3];
  const float* n2_b  = (const float*)d_in[4];
  const float* g_w1  = (const float*)d_in[5];
  const float* g_b1  = (const float*)d_in[6];
  const float* g_w2  = (const float*)d_in[7];
  const float* g_b2  = (const float*)d_in[8];
  const float* e_w1[3]  = {(const float*)d_in[9],  (const float*)d_in[16], (const float*)d_in[23]};
  const float* e_b1[3]  = {(const float*)d_in[10], (const float*)d_in[17], (const float*)d_in[24]};
  const float* e_pw[3]  = {(const float*)d_in[11], (const float*)d_in[18], (const float*)d_in[25]};
  const float* e_dw[3]  = {(const float*)d_in[12], (const float*)d_in[19], (const float*)d_in[26]};
  const float* e_dwb[3] = {(const float*)d_in[13], (const float*)d_in[20], (const float*)d_in[27]};
  const float* e_w2[3]  = {(const float*)d_in[14], (const float*)d_in[21], (const float*)d_in[28]};
  const float* e_b2[3]  = {(const float*)d_in[15], (const float*)d_in[22], (const float*)d_in[29]};
  const float* ms    = (const float*)d_in[30];
  const float* qkv_w = (const float*)d_in[31];
  const float* qkv_b = (const float*)d_in[32];
  const float* lepe_w = (const float*)d_in[33];
  const float* lepe_b = (const float*)d_in[34];
  const float* rpb   = (const float*)d_in[35];
  const float* proj_w = (const float*)d_in[36];
  const float* proj_b = (const float*)d_in[37];
  const float* fc1_w = (const float*)d_in[38];
  const float* fc1_b = (const float*)d_in[39];
  const float* ffn_dw = (const float*)d_in[40];
  const float* ffn_db = (const float*)d_in[41];
  const float* fc2_w = (const float*)d_in[42];
  const float* fc2_b = (const float*)d_in[43];
  const int*   rpi   = (const int*)d_in[44];
  float* out = (float*)d_out;

  // Arena: 384 floats/token + small tail (201.3 MB)
  const size_t M = MTOK;
  float* ws = (float*)d_ws;
  float* A   = ws;
  float* t1e[3] = { ws + 96 * M, ws + 108 * M, ws + 120 * M };
  float* t2b = ws + 132 * M;
  float* t3[3] = { ws + 144 * M, ws + 156 * M, ws + 168 * M };
  float* X   = ws + 96 * M;            // stride 288, spans [96M, 384M)
  float* T   = ws + 192 * M;           // stride 192
  float* T2  = ws;                     // stride 192
  float* O   = A;
  float* S2  = out;                    // d_out as scratch for shortcut+proj
  float* biasT = out;                  // d_out head hosts biasT (dead before step 8)
  float* pooled = ws + 384 * M;        // 192 floats
  float* gv = pooled + 192;            // 6 floats

  // 0. bias table
  bias_kernel<<<HEADS * NTOK / 256, 256, 0, stream>>>(rpi, rpb, biasT);
  // 1. LN1
  ln_kernel<<<M / 4, 256, 0, stream>>>(x, n1_g, n1_b, A);
  // 2. gate
  hipMemsetAsync(pooled, 0, 256 * sizeof(float), stream);
  pool_kernel<<<dim3(128, 2), 128, 0, stream>>>(A, pooled);
  gate_kernel<<<1, 64, 0, stream>>>(pooled, g_w1, g_b1, g_w2, g_b2, gv);
  // 3. experts: fused w1 (one A read) -> pw -> dwconv+lrelu
  mgemm3_kernel<<<1024, 256, 0, stream>>>(A, e_w1[0], e_w1[1], e_w1[2],
      e_b1[0], e_b1[1], e_b1[2], t1e[0], t1e[1], t1e[2]);
  for (int i = 0; i < 3; i++) {
    gemm_kernel<12, 12, 12, 0, false, false><<<dim3(2048, 1), 256, 0, stream>>>(
        t1e[i], e_pw[i], nullptr, nullptr, t2b, 12, 0);
    if (i == 0)
      dwconv4_kernel<3, 3, 1, false><<<M * 3 / 256, 256, 0, stream>>>(t2b, e_dw[0], e_dwb[0], nullptr, t3[0], 12, 12, 0);
    else if (i == 1)
      dwconv4_kernel<5, 3, 1, false><<<M * 3 / 256, 256, 0, stream>>>(t2b, e_dw[1], e_dwb[1], nullptr, t3[1], 12, 12, 0);
    else
      dwconv4_kernel<7, 3, 1, false><<<M * 3 / 256, 256, 0, stream>>>(t2b, e_dw[2], e_dwb[2], nullptr, t3[2], 12, 12, 0);
  }
  // 4. combine -> y2 (in place in A)
  moe_combine_kernel<<<M * 96 / 256, 256, 0, stream>>>(A,
      t3[0], t3[1], t3[2], e_w2[0], e_w2[1], e_w2[2], e_b2[0], e_b2[1], e_b2[2], gv, ms);
  // 5. qkv (MFMA)
  mgemm_kernel<96, 288, 0, false, true><<<dim3(5, 1024), 256, 0, stream>>>(
      A, qkv_w, qkv_b, nullptr, X, 288, 0);
  // 6. lepe -> O (aliases A)
  dwconv4_kernel<5, 24, 2, false><<<M * 24 / 256, 256, 0, stream>>>(X + 192, lepe_w, lepe_b, nullptr, O, 288, 96, 0);
  // 7. attention: O = lepe + attn_s @ V
  attn_kernel<<<dim3(512, 6), 256, 0, stream>>>(X, biasT, O);
  // 8. proj + shortcut -> S2 (= d_out)
  mgemm_kernel<96, 96, 0, true, true><<<dim3(2, 1024), 256, 0, stream>>>(
      O, proj_w, proj_b, x, S2, 96, 96);
  // 9. LN2 -> A
  ln_kernel<<<M / 4, 256, 0, stream>>>(S2, n2_g, n2_b, A);
  // 10. fc1 + gelu (MFMA) -> T
  mgemm_kernel<96, 192, 2, false, true><<<dim3(3, 1024), 256, 0, stream>>>(
      A, fc1_w, fc1_b, nullptr, T, 192, 0);
  // 11. conv-FFN: T2 = T + gelu(dwconv5(T))
  dwconv4_kernel<5, 48, 2, true><<<M * 48 / 256, 256, 0, stream>>>(T, ffn_dw, ffn_db, T, T2, 192, 192, 192);
  // 12. fc2 + residual (MFMA) -> out
  mgemm_kernel<192, 96, 0, true, true><<<dim3(2, 1024), 256, 0, stream>>>(
      T2, fc2_w, fc2_b, S2, out, 96, 96);
}